// Round 2
// baseline (114.888 us; speedup 1.0000x reference)
//
#include <hip/hip_runtime.h>

// Quanv: 3x3 VALID conv, x:(32,64,64,64) f32, w:(128,64,9) f32.
// Output layout replicates reference bug: out[((oc*B + b)*Ho + ho)*Wo + wo].
//
// R4: cohort-split main kernel for phase overlap.
//  - prep unchanged (fused transpose_x + pack_w, grid (64,33)).
//  - main: grid (32,32) = 1024 blocks, block = 2 ho rows x 128 oc x 64 wo.
//    Wave = (row, wo-half): acc 8x2 (64 VGPR). LDS: 32 KB x (4 rows incl halo)
//    + 2x16 KB w double-buffer = 64 KB -> 2 blocks/CU -> TWO cohorts: one
//    cohort's 63 MB epilogue store overlaps the other's stage+compute
//    (R3's 512-block grid was exactly one cohort: chip-synchronized
//    stage/compute/store phases with an exposed ~10 us store tail).
//  - weight staging: tap t+2 into freed buffer right after the tap barrier
//    (in flight under a full tap of MFMA), as R3.
// Fallback to fp32 direct conv if ws_size too small.

typedef __attribute__((ext_vector_type(8))) short short8;
typedef __attribute__((ext_vector_type(4))) float f32x4;
typedef __attribute__((ext_vector_type(4))) unsigned int uint4v;

__device__ __forceinline__ unsigned short f2bf(float f) {
    unsigned u = __builtin_bit_cast(unsigned, f);
    u = (u + 0x7FFFu + ((u >> 16) & 1u)) >> 16;   // RNE
    return (unsigned short)u;
}

__device__ __forceinline__ void glds16(const void* g, void* s) {
    __builtin_amdgcn_global_load_lds(
        (const __attribute__((address_space(1))) unsigned int*)g,
        (__attribute__((address_space(3))) unsigned int*)s, 16, 0, 0);
}

// ---------- fused prep: x -> xT (bf16, c-swizzled) ; w -> wT (bf16, c-swizzled) ----------
__global__ __launch_bounds__(256)
void prep(const float* __restrict__ x, const float* __restrict__ w,
          char* __restrict__ xT, char* __restrict__ wT) {
    __shared__ float tile[64][65];          // [c][col], +1 pad (transpose part only)
    const int tid = threadIdx.x;

    if (blockIdx.y == 32) {
        // ---- pack_w part: w (oc, c, 9) f32 -> wT[tap][oc][c-swizzled] bf16 ----
        const int id = blockIdx.x * 256 + tid;   // 0..16383, need 0..9215
        if (id < 9216) {
            const int t = id >> 10;
            const int rem = id & 1023;
            const int oc = rem >> 3, q = rem & 7;
            unsigned int wds[4];
            #pragma unroll
            for (int jj = 0; jj < 4; ++jj) {
                const unsigned short lo = f2bf(w[(size_t)oc * 576 + (q * 8 + 2 * jj + 0) * 9 + t]);
                const unsigned short hi = f2bf(w[(size_t)oc * 576 + (q * 8 + 2 * jj + 1) * 9 + t]);
                wds[jj] = (unsigned)lo | ((unsigned)hi << 16);
            }
            uint4v v; v[0] = wds[0]; v[1] = wds[1]; v[2] = wds[2]; v[3] = wds[3];
            *(uint4v*)(wT + (size_t)(t * 16384 + oc * 128) + ((q ^ (oc & 7)) * 16)) = v;
        }
        return;
    }

    // ---- transpose part: x (b,c,h,w) f32 -> xT[b][h][col][c-swizzled] bf16 ----
    const int h = blockIdx.x, b = blockIdx.y;

    #pragma unroll
    for (int i = 0; i < 4; ++i) {
        const int idx = i * 256 + tid;
        const int c = idx >> 4, j = idx & 15;
        const float4 v = *(const float4*)(x + (size_t)(((b * 64 + c) * 64 + h) * 64 + j * 4));
        tile[c][j * 4 + 0] = v.x; tile[c][j * 4 + 1] = v.y;
        tile[c][j * 4 + 2] = v.z; tile[c][j * 4 + 3] = v.w;
    }
    __syncthreads();

    #pragma unroll
    for (int i = 0; i < 2; ++i) {
        const int idx = i * 256 + tid;
        const int col = idx >> 3, q = idx & 7;
        unsigned int wds[4];
        #pragma unroll
        for (int jj = 0; jj < 4; ++jj) {
            const unsigned short lo = f2bf(tile[q * 8 + 2 * jj + 0][col]);
            const unsigned short hi = f2bf(tile[q * 8 + 2 * jj + 1][col]);
            wds[jj] = (unsigned)lo | ((unsigned)hi << 16);
        }
        uint4v v; v[0] = wds[0]; v[1] = wds[1]; v[2] = wds[2]; v[3] = wds[3];
        *(uint4v*)(xT + (size_t)(((b * 64 + h) * 64 + col) * 128) + ((q ^ (col & 7)) * 16)) = v;
    }
}

// ---------- main MFMA kernel ----------
__global__ __launch_bounds__(256, 2)
void quanv_mfma(const char* __restrict__ xT, const char* __restrict__ wT,
                float* __restrict__ out) {
    __shared__ __align__(16) char lds[65536];
    char* sx  = lds;            // 32 KB: [4 rows][64 col][128B c-block swizzled]
    char* sw0 = lds + 32768;    // 16 KB: even taps  [128 oc][128B c-block swizzled]
    char* sw1 = lds + 49152;    // 16 KB: odd taps

    const int tid = threadIdx.x;
    const int lane = tid & 63;
    const int wid = tid >> 6;
    const int hot = blockIdx.x;   // 0..31
    const int b   = blockIdx.y;   // 0..31
    const int ho0 = hot * 2;

    // stage x: 4 rows x 8 KB = 32 chunks of 1 KB (async, direct to LDS)
    for (int k = wid; k < 32; k += 4) {
        const int r = k >> 3, sub = k & 7;
        int gr = ho0 + r; if (gr > 63) gr = 63;
        glds16(xT + (size_t)((b * 64 + gr) * 8192 + sub * 1024 + lane * 16),
               sx + k * 1024);
    }
    // stage weights for tap 0 -> sw0 and tap 1 -> sw1
    for (int k = wid; k < 16; k += 4) {
        glds16(wT + (size_t)(k * 1024 + lane * 16),         sw0 + k * 1024);
        glds16(wT + (size_t)(16384 + k * 1024 + lane * 16), sw1 + k * 1024);
    }
    __syncthreads();   // drains vmcnt then barrier

    const int l15 = lane & 15;
    const int quad = lane >> 4;
    const int r    = wid >> 1;          // output row within tile (0..1)
    const int half = wid & 1;           // wo half (0: wo 0-31, 1: wo 32-63)
    const int ho = ho0 + r;

    f32x4 acc[8][2];
    #pragma unroll
    for (int mt = 0; mt < 8; ++mt)
        #pragma unroll
        for (int nt = 0; nt < 2; ++nt)
            acc[mt][nt] = (f32x4){0.f, 0.f, 0.f, 0.f};

    #pragma unroll
    for (int tap = 0; tap < 9; ++tap) {
        const int kh = tap / 3, kw = tap % 3;
        char* swc = (tap & 1) ? sw1 : sw0;    // buffer holding tap's weights

        #pragma unroll
        for (int s = 0; s < 2; ++s) {           // K halves (c 0..31, 32..63)
            const int q = s * 4 + quad;         // c-chunk index 0..7
            short8 a[8], bf[2];
            const int abase = l15 * 128 + ((q ^ (l15 & 7)) * 16);
            #pragma unroll
            for (int mt = 0; mt < 8; ++mt)
                a[mt] = *(const short8*)(swc + abase + mt * 2048);
            #pragma unroll
            for (int nt = 0; nt < 2; ++nt) {
                const int cb = kw + half * 32 + nt * 16 + l15;   // input column
                const int bbase = (r + kh) * 8192 + cb * 128 + ((q ^ (cb & 7)) * 16);
                bf[nt] = *(const short8*)(sx + bbase);
            }
            #pragma unroll
            for (int mt = 0; mt < 8; ++mt)
                #pragma unroll
                for (int nt = 0; nt < 2; ++nt)
                    acc[mt][nt] = __builtin_amdgcn_mfma_f32_16x16x32_bf16(
                        a[mt], bf[nt], acc[mt][nt], 0, 0, 0);
        }

        if (tap < 8) {
            __syncthreads();                    // all waves done reading swc;
                                                // also drains the tap+1 stage
                                                // issued one iteration ago
            if (tap < 7) {
                // refill the just-freed buffer with tap+2's weights; these
                // loads fly under the whole of tap+1's compute and are
                // drained by the next __syncthreads.
                for (int k = wid; k < 16; k += 4)
                    glds16(wT + (size_t)((tap + 2) * 16384 + k * 1024 + lane * 16),
                           swc + k * 1024);
            }
        }
    }

    // epilogue: C/D layout col=lane&15 (wo), row=quad*4+reg (oc within tile)
    if (ho < 62) {
        #pragma unroll
        for (int mt = 0; mt < 8; ++mt) {
            #pragma unroll
            for (int i = 0; i < 4; ++i) {
                const int oc = mt * 16 + quad * 4 + i;
                float* op = out + ((size_t)(oc * 32 + b) * 62 + ho) * 62;
                #pragma unroll
                for (int nt = 0; nt < 2; ++nt) {
                    const int wo = half * 32 + nt * 16 + l15;
                    if (wo < 62) op[wo] = acc[mt][nt][i];
                }
            }
        }
    }
}

// ---------- fallback: fp32 direct conv (used only if ws too small) ----------
#define CCH   8
#define OC_PT 8
#define ROWS  18
__global__ __launch_bounds__(256, 4)
void quanv_f32(const float* __restrict__ x, const float* __restrict__ w,
               float* __restrict__ out) {
    __shared__ float sx_raw[CCH * ROWS * 64 + 4];
    #define SX(cl, row, col) sx_raw[((cl) * ROWS + (row)) * 64 + (col)]
    const int tid = threadIdx.x;
    const int tx = tid & 15, ty = tid >> 4;
    const int hot = blockIdx.x, ocg = blockIdx.y, b = blockIdx.z;
    const int row0 = hot * 16, ho = row0 + ty, wo0 = tx * 4;
    const float* xb = x + (size_t)b * (64 * 64 * 64);
    const float* wb = w + (size_t)(ocg * OC_PT) * 576;
    float acc[OC_PT][4];
    #pragma unroll
    for (int o = 0; o < OC_PT; ++o)
        #pragma unroll
        for (int q = 0; q < 4; ++q) acc[o][q] = 0.f;
    for (int cc = 0; cc < 64; cc += CCH) {
        __syncthreads();
        #pragma unroll
        for (int j = 0; j < 9; ++j) {
            const int idx = j * 256 + tid;
            const int col4 = idx & 15, rowc = idx >> 4;
            const int row = rowc % ROWS, cl = rowc / ROWS;
            int gr = row0 + row; if (gr > 63) gr = 63;
            *(float4*)(&sx_raw[idx * 4]) =
                *(const float4*)(xb + ((size_t)(cc + cl) * 64 + gr) * 64 + col4 * 4);
        }
        __syncthreads();
        for (int cl = 0; cl < CCH; ++cl) {
            float xv[3][6];
            #pragma unroll
            for (int kh = 0; kh < 3; ++kh)
                #pragma unroll
                for (int j = 0; j < 6; ++j) xv[kh][j] = SX(cl, ty + kh, wo0 + j);
            const float* wc = wb + (size_t)(cc + cl) * 9;
            #pragma unroll
            for (int o = 0; o < OC_PT; ++o) {
                float wv[9];
                #pragma unroll
                for (int t = 0; t < 9; ++t) wv[t] = wc[(size_t)o * 576 + t];
                #pragma unroll
                for (int kh = 0; kh < 3; ++kh)
                    #pragma unroll
                    for (int kw = 0; kw < 3; ++kw) {
                        const float wvv = wv[kh * 3 + kw];
                        #pragma unroll
                        for (int q = 0; q < 4; ++q)
                            acc[o][q] = fmaf(xv[kh][kw + q], wvv, acc[o][q]);
                    }
            }
        }
    }
    if (ho < 62) {
        #pragma unroll
        for (int o = 0; o < OC_PT; ++o) {
            const int oc = ocg * OC_PT + o;
            float* op = out + ((size_t)(oc * 32 + b) * 62 + ho) * 62 + wo0;
            #pragma unroll
            for (int q = 0; q < 4; ++q)
                if (wo0 + q < 62) op[q] = acc[o][q];
        }
    }
    #undef SX
}

extern "C" void kernel_launch(void* const* d_in, const int* in_sizes, int n_in,
                              void* d_out, int out_size, void* d_ws, size_t ws_size,
                              hipStream_t stream) {
    const float* x = (const float*)d_in[0];
    const float* w = (const float*)d_in[1];
    float* out = (float*)d_out;

    const size_t XT_BYTES = 16777216;   // 32*64*64*64 bf16
    const size_t WT_BYTES = 147456;     // 9*128*64 bf16

    if (ws_size >= XT_BYTES + WT_BYTES) {
        char* xT = (char*)d_ws;
        char* wT = (char*)d_ws + XT_BYTES;
        prep<<<dim3(64, 33), 256, 0, stream>>>(x, w, xT, wT);
        quanv_mfma<<<dim3(32, 32), 256, 0, stream>>>(xT, wT, out);
    } else {
        quanv_f32<<<dim3(4, 16, 32), 256, 0, stream>>>(x, w, out);
    }
}

// Round 3
// 108.769 us; speedup vs baseline: 1.0563x; 1.0563x over previous
//
#include <hip/hip_runtime.h>

// Quanv: 3x3 VALID conv, x:(32,64,64,64) f32, w:(128,64,9) f32.
// Output layout replicates reference bug: out[((oc*B + b)*Ho + ho)*Wo + wo].
//
// R5: fully fused main kernel (transpose folded into MFMA kernel).
//  - pack_w: tiny standalone kernel, w -> wT[tap][oc][c-swizzled] bf16 (144 KB,
//    L2-resident; ~2 us).
//  - main: grid 512 blocks (16 ho-tiles x 32 b, XCD-swizzled so each XCD owns
//    4 whole batch images -> halo + wT reads stay in local L2). Block = 4 ho
//    rows x 128 oc x 64 wo, 4 waves, acc 8x4 (R3 geometry — R4's 2-row split
//    regressed). Staging reads x DIRECTLY from NCHW f32 (64-lane coalesced,
//    lanes span w), converts f32->bf16 in-register, ds_write_b128 into the
//    same XOR-swizzled sx layout as before. No xT intermediate: saves 16.8 MB
//    write + 24.6 MB read and the prep kernel's serial wall.
//  - weights double-buffered in LDS via global_load_lds (tap t+2 staged right
//    after the tap barrier, in flight under a full tap of MFMA).
//  - LDS 48 KB sx + 2x16 KB w = 80 KB -> 2 blocks/CU.
// Fallback to fp32 direct conv if ws_size too small for wT.

typedef __attribute__((ext_vector_type(8))) short short8;
typedef __attribute__((ext_vector_type(4))) float f32x4;
typedef __attribute__((ext_vector_type(4))) unsigned int uint4v;

__device__ __forceinline__ unsigned short f2bf(float f) {
    unsigned u = __builtin_bit_cast(unsigned, f);
    u = (u + 0x7FFFu + ((u >> 16) & 1u)) >> 16;   // RNE
    return (unsigned short)u;
}

__device__ __forceinline__ void glds16(const void* g, void* s) {
    __builtin_amdgcn_global_load_lds(
        (const __attribute__((address_space(1))) unsigned int*)g,
        (__attribute__((address_space(3))) unsigned int*)s, 16, 0, 0);
}

// ---------- pack_w: w (oc, c, 9) f32 -> wT[tap][oc][c-swizzled] bf16 ----------
__global__ __launch_bounds__(256)
void pack_w(const float* __restrict__ w, char* __restrict__ wT) {
    const int id = blockIdx.x * 256 + threadIdx.x;   // 0..9215
    if (id >= 9216) return;
    const int t = id >> 10;
    const int rem = id & 1023;
    const int oc = rem >> 3, q = rem & 7;
    unsigned int wds[4];
    #pragma unroll
    for (int jj = 0; jj < 4; ++jj) {
        const unsigned short lo = f2bf(w[(size_t)oc * 576 + (q * 8 + 2 * jj + 0) * 9 + t]);
        const unsigned short hi = f2bf(w[(size_t)oc * 576 + (q * 8 + 2 * jj + 1) * 9 + t]);
        wds[jj] = (unsigned)lo | ((unsigned)hi << 16);
    }
    uint4v v; v[0] = wds[0]; v[1] = wds[1]; v[2] = wds[2]; v[3] = wds[3];
    *(uint4v*)(wT + (size_t)(t * 16384 + oc * 128) + ((q ^ (oc & 7)) * 16)) = v;
}

// ---------- fused main MFMA kernel ----------
__global__ __launch_bounds__(256, 2)
void quanv_fused(const float* __restrict__ x, const char* __restrict__ wT,
                 float* __restrict__ out) {
    __shared__ __align__(16) char lds[81920];
    char* sx  = lds;            // 48 KB: [6 rows][64 col][128B c-block swizzled]
    char* sw0 = lds + 49152;    // 16 KB: even taps  [128 oc][128B c-block swizzled]
    char* sw1 = lds + 65536;    // 16 KB: odd taps

    const int tid = threadIdx.x;
    const int lane = tid & 63;
    const int wid = tid >> 6;

    // bijective XCD swizzle: 512 blocks, 8 XCDs -> each XCD gets a contiguous
    // 64-block chunk = 4 whole b-images (all hot) -> halo/wT L2-local.
    const int bidl = blockIdx.x + 16 * blockIdx.y;     // dispatch-linear 0..511
    const int sbid = (bidl & 7) * 64 + (bidl >> 3);
    const int hot = sbid & 15;    // 0..15
    const int b   = sbid >> 4;    // 0..31
    const int ho0 = hot * 4;

    // ---- stage weights for tap 0 -> sw0 and tap 1 -> sw1 (async; latency
    //      hidden under the x staging below) ----
    for (int k = wid; k < 16; k += 4) {
        glds16(wT + (size_t)(k * 1024 + lane * 16),         sw0 + k * 1024);
        glds16(wT + (size_t)(16384 + k * 1024 + lane * 16), sw1 + k * 1024);
    }

    // ---- stage x: direct NCHW f32 -> bf16 transposed into sx ----
    // task = (row 0..5, q 0..7, col 0..63); 3072 tasks / 256 threads = 12.
    // Global loads: 64 lanes span col -> 256 B contiguous per instruction.
    const float* xb = x + (size_t)b * 262144;
    #pragma unroll
    for (int i = 0; i < 12; ++i) {
        const int task = i * 256 + tid;
        const int col = task & 63;
        const int rem = task >> 6;        // 0..47
        const int q = rem & 7, row = rem >> 3;
        int gr = ho0 + row; if (gr > 63) gr = 63;
        const float* src = xb + (size_t)(q * 8) * 4096 + gr * 64 + col;
        float f[8];
        #pragma unroll
        for (int e = 0; e < 8; ++e) f[e] = src[(size_t)e * 4096];
        unsigned wds[4];
        #pragma unroll
        for (int jj = 0; jj < 4; ++jj)
            wds[jj] = (unsigned)f2bf(f[2 * jj]) | ((unsigned)f2bf(f[2 * jj + 1]) << 16);
        uint4v v; v[0] = wds[0]; v[1] = wds[1]; v[2] = wds[2]; v[3] = wds[3];
        *(uint4v*)(sx + (size_t)(row * 8192 + col * 128) + ((q ^ (col & 7)) * 16)) = v;
    }
    __syncthreads();   // drains vmcnt (weights) + lgkmcnt (sx writes), then barrier

    const int l15 = lane & 15;
    const int quad = lane >> 4;
    const int r = wid;            // output row within tile
    const int ho = ho0 + r;

    f32x4 acc[8][4];
    #pragma unroll
    for (int mt = 0; mt < 8; ++mt)
        #pragma unroll
        for (int nt = 0; nt < 4; ++nt)
            acc[mt][nt] = (f32x4){0.f, 0.f, 0.f, 0.f};

    #pragma unroll
    for (int tap = 0; tap < 9; ++tap) {
        const int kh = tap / 3, kw = tap % 3;
        char* swc = (tap & 1) ? sw1 : sw0;    // buffer holding tap's weights

        #pragma unroll
        for (int s = 0; s < 2; ++s) {           // K halves (c 0..31, 32..63)
            const int q = s * 4 + quad;         // c-chunk index 0..7
            short8 a[8], bf[4];
            const int abase = l15 * 128 + ((q ^ (l15 & 7)) * 16);
            #pragma unroll
            for (int mt = 0; mt < 8; ++mt)
                a[mt] = *(const short8*)(swc + abase + mt * 2048);
            const int cb = kw + l15;            // lane's column (before n-tile)
            const int bbase = (r + kh) * 8192 + cb * 128 + ((q ^ (cb & 7)) * 16);
            #pragma unroll
            for (int nt = 0; nt < 4; ++nt)
                bf[nt] = *(const short8*)(sx + bbase + nt * 2048);
            #pragma unroll
            for (int mt = 0; mt < 8; ++mt)
                #pragma unroll
                for (int nt = 0; nt < 4; ++nt)
                    acc[mt][nt] = __builtin_amdgcn_mfma_f32_16x16x32_bf16(
                        a[mt], bf[nt], acc[mt][nt], 0, 0, 0);
        }

        if (tap < 8) {
            __syncthreads();                    // all waves done reading swc;
                                                // also drains the tap+1 stage
                                                // issued one iteration ago
            if (tap < 7) {
                // refill the just-freed buffer with tap+2's weights; these
                // loads fly under the whole of tap+1's compute and are
                // drained by the next __syncthreads.
                for (int k = wid; k < 16; k += 4)
                    glds16(wT + (size_t)((tap + 2) * 16384 + k * 1024 + lane * 16),
                           swc + k * 1024);
            }
        }
    }

    // epilogue: C/D layout col=lane&15 (wo), row=quad*4+reg (oc within tile)
    if (ho < 62) {
        #pragma unroll
        for (int mt = 0; mt < 8; ++mt) {
            #pragma unroll
            for (int i = 0; i < 4; ++i) {
                const int oc = mt * 16 + quad * 4 + i;
                float* op = out + ((size_t)(oc * 32 + b) * 62 + ho) * 62;
                #pragma unroll
                for (int nt = 0; nt < 4; ++nt) {
                    const int wo = nt * 16 + l15;
                    if (wo < 62) op[wo] = acc[mt][nt][i];
                }
            }
        }
    }
}

// ---------- fallback: fp32 direct conv (used only if ws too small) ----------
#define CCH   8
#define OC_PT 8
#define ROWS  18
__global__ __launch_bounds__(256, 4)
void quanv_f32(const float* __restrict__ x, const float* __restrict__ w,
               float* __restrict__ out) {
    __shared__ float sx_raw[CCH * ROWS * 64 + 4];
    #define SX(cl, row, col) sx_raw[((cl) * ROWS + (row)) * 64 + (col)]
    const int tid = threadIdx.x;
    const int tx = tid & 15, ty = tid >> 4;
    const int hot = blockIdx.x, ocg = blockIdx.y, b = blockIdx.z;
    const int row0 = hot * 16, ho = row0 + ty, wo0 = tx * 4;
    const float* xb = x + (size_t)b * (64 * 64 * 64);
    const float* wb = w + (size_t)(ocg * OC_PT) * 576;
    float acc[OC_PT][4];
    #pragma unroll
    for (int o = 0; o < OC_PT; ++o)
        #pragma unroll
        for (int q = 0; q < 4; ++q) acc[o][q] = 0.f;
    for (int cc = 0; cc < 64; cc += CCH) {
        __syncthreads();
        #pragma unroll
        for (int j = 0; j < 9; ++j) {
            const int idx = j * 256 + tid;
            const int col4 = idx & 15, rowc = idx >> 4;
            const int row = rowc % ROWS, cl = rowc / ROWS;
            int gr = row0 + row; if (gr > 63) gr = 63;
            *(float4*)(&sx_raw[idx * 4]) =
                *(const float4*)(xb + ((size_t)(cc + cl) * 64 + gr) * 64 + col4 * 4);
        }
        __syncthreads();
        for (int cl = 0; cl < CCH; ++cl) {
            float xv[3][6];
            #pragma unroll
            for (int kh = 0; kh < 3; ++kh)
                #pragma unroll
                for (int j = 0; j < 6; ++j) xv[kh][j] = SX(cl, ty + kh, wo0 + j);
            const float* wc = wb + (size_t)(cc + cl) * 9;
            #pragma unroll
            for (int o = 0; o < OC_PT; ++o) {
                float wv[9];
                #pragma unroll
                for (int t = 0; t < 9; ++t) wv[t] = wc[(size_t)o * 576 + t];
                #pragma unroll
                for (int kh = 0; kh < 3; ++kh)
                    #pragma unroll
                    for (int kw = 0; kw < 3; ++kw) {
                        const float wvv = wv[kh * 3 + kw];
                        #pragma unroll
                        for (int q = 0; q < 4; ++q)
                            acc[o][q] = fmaf(xv[kh][kw + q], wvv, acc[o][q]);
                    }
            }
        }
    }
    if (ho < 62) {
        #pragma unroll
        for (int o = 0; o < OC_PT; ++o) {
            const int oc = ocg * OC_PT + o;
            float* op = out + ((size_t)(oc * 32 + b) * 62 + ho) * 62 + wo0;
            #pragma unroll
            for (int q = 0; q < 4; ++q)
                if (wo0 + q < 62) op[q] = acc[o][q];
        }
    }
    #undef SX
}

extern "C" void kernel_launch(void* const* d_in, const int* in_sizes, int n_in,
                              void* d_out, int out_size, void* d_ws, size_t ws_size,
                              hipStream_t stream) {
    const float* x = (const float*)d_in[0];
    const float* w = (const float*)d_in[1];
    float* out = (float*)d_out;

    const size_t WT_BYTES = 147456;     // 9*128*64 bf16

    if (ws_size >= WT_BYTES) {
        char* wT = (char*)d_ws;
        pack_w<<<36, 256, 0, stream>>>(w, wT);
        quanv_fused<<<dim3(16, 32), 256, 0, stream>>>(x, wT, out);
    } else {
        quanv_f32<<<dim3(4, 16, 32), 256, 0, stream>>>(x, w, out);
    }
}